// Round 1
// baseline (238.018 us; speedup 1.0000x reference)
//
#include <hip/hip_runtime.h>
#include <stdint.h>

// MHA forward, B=8 T=1024 C=1024 H=16 D=64.
// cast3 -> QKV GEMM (NEW: 256x256 8-phase counted-vmcnt template, T2+T3+T4+T5;
// writes packed QK [stride 2048, Q pre-scaled] + V^T directly)
// -> flash attention (512-thr blocks, 128-row q-tile pairs, peeled causal mask,
// deferred l-reduction) -> proj GEMM (old 128x128 structure, +bias, fp32).
// 4 launches.

#define Bn 8
#define Tn 1024
#define Cn 1024
#define Hn 16
#define Dn 64
#define Mn (Bn * Tn)      // 8192
#define NQKV (3 * Cn)     // 3072
#define QKS 2048          // packed QK row stride
#define NTILE 16          // K / 64 for the 256^2 GEMM
#define GQKV_BLOCKS 384   // (8192/256) * (3072/256)

typedef unsigned short u16;
typedef float f32x4 __attribute__((ext_vector_type(4)));
typedef __bf16 bf16x8 __attribute__((ext_vector_type(8)));
typedef unsigned short ushx8 __attribute__((ext_vector_type(8)));
typedef unsigned short ushx4 __attribute__((ext_vector_type(4)));

__device__ __forceinline__ u16 f2bf(float f) {
  unsigned int u = __float_as_uint(f);
  u += 0x7fffu + ((u >> 16) & 1u);   // RTN-even
  return (u16)(u >> 16);
}
__device__ __forceinline__ u16 f2bf_rna(float f) {
  return (u16)((__float_as_uint(f) + 0x8000u) >> 16);
}

__device__ __forceinline__ f32x4 mfma_bf16(ushx8 a, ushx8 b, f32x4 c) {
  return __builtin_amdgcn_mfma_f32_16x16x32_bf16(
      __builtin_bit_cast(bf16x8, a), __builtin_bit_cast(bf16x8, b), c, 0, 0, 0);
}

// async global->LDS, 16B per lane; LDS dest = wave-uniform base + lane*16 (m104)
__device__ __forceinline__ void async16(const u16* g, u16* l) {
  __builtin_amdgcn_global_load_lds(
      (__attribute__((address_space(1))) void*)(void*)g,
      (__attribute__((address_space(3))) void*)l, 16, 0, 0);
}

// ---- DPP 16-lane butterfly reductions (VALU-rate, no LDS pipe) ----
template <int CTRL>
__device__ __forceinline__ float dppmov(float v) {
  return __builtin_bit_cast(float, __builtin_amdgcn_update_dpp(
      0, __builtin_bit_cast(int, v), CTRL, 0xf, 0xf, true));
}
__device__ __forceinline__ float red16max(float v) {
  v = fmaxf(v, dppmov<0xB1>(v));
  v = fmaxf(v, dppmov<0x4E>(v));
  v = fmaxf(v, dppmov<0x141>(v));
  v = fmaxf(v, dppmov<0x140>(v));
  return v;
}
__device__ __forceinline__ float red16sum(float v) {
  v += dppmov<0xB1>(v);
  v += dppmov<0x4E>(v);
  v += dppmov<0x141>(v);
  v += dppmov<0x140>(v);
  return v;
}

// ---------------- fused cast fp32 -> bf16 (3 tensors, 1 launch) ----------------
__global__ void cast3_kernel(const float* __restrict__ a, u16* __restrict__ oa, int na4,
                             const float* __restrict__ b, u16* __restrict__ ob, int nb4,
                             const float* __restrict__ c, u16* __restrict__ oc, int nc4) {
  int i = blockIdx.x * blockDim.x + threadIdx.x;
  const float* in;
  u16* out;
  if (i < na4) { in = a; out = oa; }
  else if (i < na4 + nb4) { in = b; out = ob; i -= na4; }
  else if (i < na4 + nb4 + nc4) { in = c; out = oc; i -= na4 + nb4; }
  else return;
  float4 v = ((const float4*)in)[i];
  ushx4 o = { f2bf(v.x), f2bf(v.y), f2bf(v.z), f2bf(v.w) };
  ((ushx4*)out)[i] = o;
}

#define SLOG2E 0.18033688011112042f

// ---------------- QKV GEMM: 256x256 tile, BK=64, 8-phase counted-vmcnt ----------------
// 512 threads = 8 waves (2 Mx4 N); per-wave 128x64 output = acc[8][4].
// LDS 128 KiB: A at 0, B at +32768 (u16), each [dbuf][khalf][256 rows][32 k] with
// chunk swizzle p = q ^ ((row>>1)&3) (conflict-free, same family as old kernel).
// Half-tile (one [256][32] region, 16 KB) staged by 2 async16/thread, linear dest,
// pre-swizzled global source. Per 2 K-tiles: 8 phases; vmcnt(4) at phases 4+8 only.
// Stage schedule (iteration computes tiles t=2it,t+1; buf = tile&1):
//   P1: (t+1).Ak1+(t+1).Bk1 -> buf1   (slots last read P7/P8 of prev iter)
//   P3: (t+2).Ak0 -> buf0             (last read P2)
//   P4: (t+2).Bk0 -> buf0 ; vmcnt(4)  (confirms P1's stages for P7 reads)
//   P5: (t+2).Ak1+(t+2).Bk1 -> buf0   (last read P4)
//   P7: (t+3).Ak0 -> buf1             (last read P6)
//   P8: (t+3).Bk0 -> buf1 ; vmcnt(4)  (confirms P3/P4/P5 for next-iter reads)
// Compute: P1:buf0 kk0 m0-3, P2:kk0 m4-7, P3:kk1 m0-3, P4:kk1 m4-7, P5-P8 same buf1.
__global__ __launch_bounds__(512, 2) void gemm256_qkv(
    const u16* __restrict__ A, const u16* __restrict__ Bw,
    u16* __restrict__ qk, u16* __restrict__ vt) {
  __shared__ alignas(16) u16 lds[65536];  // 128 KiB

  const int tid = threadIdx.x;
  const int lane = tid & 63;
  const int wv = tid >> 6;       // 0..7
  const int quad = lane >> 4;
  const int l16 = lane & 15;
  const int wr = wv >> 2;        // 0..1
  const int wc = wv & 3;         // 0..3

  // XCD-aware swizzle (384 % 8 == 0 -> simple form is bijective)
  const int z = (blockIdx.x & 7) * (GQKV_BLOCKS / 8) + (blockIdx.x >> 3);
  const int m0 = (z & 31) * 256;   // 32 m-tiles
  const int n0 = (z >> 5) * 256;   // 12 n-tiles

  const u16* gA = A + (size_t)m0 * Cn;
  const u16* gB = Bw + (size_t)n0 * Cn;

  // staging source offsets: chunk c = l*512+tid -> row c>>2, stored chunk c&3,
  // logical k-chunk q = (c&3) ^ ((row>>1)&3)  (inverse == same XOR)
  const int r0s = tid >> 2;
  const int q0s = (tid & 3) ^ ((r0s >> 1) & 3);
  const int c1s = 512 + tid;
  const int r1s = c1s >> 2;
  const int q1s = (c1s & 3) ^ ((r1s >> 1) & 3);
  const int so0 = r0s * Cn + q0s * 8;
  const int so1 = r1s * Cn + q1s * 8;

  auto stage = [&](int region, int buf, int kk, const u16* gbase, int kt) {
    u16* dst = lds + region + (buf * 2 + kk) * 8192 + tid * 8;
    const u16* src = gbase + kt * 64 + kk * 32;
    async16(src + so0, dst);
    async16(src + so1, dst + 4096);
  };

  // fragment read offsets (u16, within one [256][32] half-region)
  const int sread = (quad ^ ((l16 >> 1) & 3)) * 8;
  const int aoff = (wr * 128 + l16) * 32 + sread;           // + mg*2048 + mi*512
  const int boff = 32768 + (wc * 64 + l16) * 32 + sread;    // + ni*512

  f32x4 acc[8][4];
#pragma unroll
  for (int i = 0; i < 8; ++i)
#pragma unroll
    for (int j = 0; j < 4; ++j) acc[i][j] = (f32x4){0.f, 0.f, 0.f, 0.f};
  ushx8 af[4], bfr[4];

  // prologue: tile0 fully + tile1 khalf0 (12 loads); vmcnt(4) leaves tile1.k0
  stage(0, 0, 0, gA, 0);      stage(32768, 0, 0, gB, 0);
  stage(0, 0, 1, gA, 0);      stage(32768, 0, 1, gB, 0);
  stage(0, 1, 0, gA, 1);      stage(32768, 1, 0, gB, 1);
  asm volatile("s_waitcnt vmcnt(4)" ::: "memory");
  __builtin_amdgcn_s_barrier();
  asm volatile("" ::: "memory");

#define PH(buf, kk, mg, LOADB, DOVM, ...)                                      \
  {                                                                            \
    const u16* hb_ = lds + ((buf) * 2 + (kk)) * 8192;                          \
    const u16* ab_ = hb_ + aoff + (mg) * 2048;                                 \
    af[0] = *(const ushx8*)(ab_);                                              \
    af[1] = *(const ushx8*)(ab_ + 512);                                        \
    af[2] = *(const ushx8*)(ab_ + 1024);                                       \
    af[3] = *(const ushx8*)(ab_ + 1536);                                       \
    if (LOADB) {                                                               \
      const u16* bb_ = hb_ + boff;                                             \
      bfr[0] = *(const ushx8*)(bb_);                                           \
      bfr[1] = *(const ushx8*)(bb_ + 512);                                     \
      bfr[2] = *(const ushx8*)(bb_ + 1024);                                    \
      bfr[3] = *(const ushx8*)(bb_ + 1536);                                    \
    }                                                                          \
    __VA_ARGS__;                                                               \
    asm volatile("" ::: "memory");                                             \
    __builtin_amdgcn_s_barrier();                                              \
    asm volatile("s_waitcnt lgkmcnt(0)" ::: "memory");                         \
    __builtin_amdgcn_s_setprio(1);                                             \
    _Pragma("unroll") for (int mi_ = 0; mi_ < 4; ++mi_) {                      \
      _Pragma("unroll") for (int ni_ = 0; ni_ < 4; ++ni_) {                    \
        acc[(mg) * 4 + mi_][ni_] =                                             \
            mfma_bf16(af[mi_], bfr[ni_], acc[(mg) * 4 + mi_][ni_]);            \
      }                                                                        \
    }                                                                          \
    __builtin_amdgcn_s_setprio(0);                                             \
    if (DOVM) asm volatile("s_waitcnt vmcnt(4)" ::: "memory");                 \
    asm volatile("" ::: "memory");                                             \
    __builtin_amdgcn_s_barrier();                                              \
    asm volatile("" ::: "memory");                                             \
  }

#pragma unroll 1
  for (int it = 0; it < 8; ++it) {
    const int t = it * 2;
    const int ktp1 = t + 1;
    const int kt2 = (t + 2 < NTILE) ? t + 2 : NTILE - 1;  // clamp: uniform vmcnt math
    const int kt3 = (t + 3 < NTILE) ? t + 3 : NTILE - 1;
    PH(0, 0, 0, 1, 0, stage(0, 1, 1, gA, ktp1); stage(32768, 1, 1, gB, ktp1))
    PH(0, 0, 1, 0, 0, )
    PH(0, 1, 0, 1, 0, stage(0, 0, 0, gA, kt2))
    PH(0, 1, 1, 0, 1, stage(32768, 0, 0, gB, kt2))
    PH(1, 0, 0, 1, 0, stage(0, 0, 1, gA, kt2); stage(32768, 0, 1, gB, kt2))
    PH(1, 0, 1, 0, 0, )
    PH(1, 1, 0, 1, 0, stage(0, 1, 0, gA, kt3))
    PH(1, 1, 1, 0, 1, stage(32768, 1, 0, gB, kt3))
  }
#undef PH
  asm volatile("s_waitcnt vmcnt(0)" ::: "memory");

  // epilogue: packed QK (Q pre-scaled) or V^T, same mapping as old kernel
  if (n0 < 2 * Cn) {
    const float sc = (n0 < Cn) ? SLOG2E : 1.f;
#pragma unroll
    for (int mi = 0; mi < 8; ++mi) {
#pragma unroll
      for (int ni = 0; ni < 4; ++ni) {
        const int col = n0 + wc * 64 + ni * 16 + l16;
        const int row = m0 + wr * 128 + mi * 16 + quad * 4;
#pragma unroll
        for (int i = 0; i < 4; ++i)
          qk[(size_t)(row + i) * QKS + col] = f2bf(acc[mi][ni][i] * sc);
      }
    }
  } else {
#pragma unroll
    for (int mi = 0; mi < 8; ++mi) {
#pragma unroll
      for (int ni = 0; ni < 4; ++ni) {
        const int colV = n0 - 2 * Cn + wc * 64 + ni * 16 + l16;  // 0..1023
        const int hh = colV >> 6, dd = colV & 63;
        const int row0 = m0 + wr * 128 + mi * 16 + quad * 4;
        const int bb = row0 >> 10, tt = row0 & 1023;
        unsigned int lo = (unsigned int)f2bf(acc[mi][ni][0]) |
                          ((unsigned int)f2bf(acc[mi][ni][1]) << 16);
        unsigned int hi = (unsigned int)f2bf(acc[mi][ni][2]) |
                          ((unsigned int)f2bf(acc[mi][ni][3]) << 16);
        uint2 pk = {lo, hi};
        *(uint2*)&vt[((size_t)(bb * Hn + hh) * Dn + dd) * Tn + tt] = pk;
      }
    }
  }
}

// ---------------- GEMM (round-6 structure; used for proj only) ----------------
// 128x128 block, 2x2 waves, BK=32, single-buffered LDS staging via async DMA.
// QKV=0: fp32 out + bias.
template <int QKV>
__global__ __launch_bounds__(256, 4) void gemm_bt(
    const u16* __restrict__ A, const u16* __restrict__ Bw,
    void* __restrict__ Cout, u16* __restrict__ vt,
    const float* __restrict__ bias, int N, int K) {
  __shared__ alignas(16) u16 As[128 * 32];
  __shared__ alignas(16) u16 Bs[128 * 32];

  const int tid = threadIdx.x;
  const int lane = tid & 63;
  const int wv = tid >> 6;
  const int quad = lane >> 4;
  const int l16 = lane & 15;
  const int m0 = blockIdx.x * 128;
  const int n0 = blockIdx.y * 128;
  const int wm = (wv >> 1) * 64;
  const int wn = (wv & 1) * 64;

  f32x4 acc[4][4];
#pragma unroll
  for (int i = 0; i < 4; ++i)
#pragma unroll
    for (int j = 0; j < 4; ++j) acc[i][j] = (f32x4){0.f, 0.f, 0.f, 0.f};

  const int r0 = tid >> 2;
  const int cc0 = tid & 3;
  const int gkc0 = cc0 ^ ((r0 >> 1) & 3);
  const int r1 = r0 + 64;
  const int gkc1 = cc0 ^ ((r1 >> 1) & 3);
  const u16* gA0 = A + (size_t)(m0 + r0) * K + gkc0 * 8;
  const u16* gA1 = A + (size_t)(m0 + r1) * K + gkc1 * 8;
  const u16* gB0 = Bw + (size_t)(n0 + r0) * K + gkc0 * 8;
  const u16* gB1 = Bw + (size_t)(n0 + r1) * K + gkc1 * 8;
  u16* lA0 = As + tid * 8;
  u16* lA1 = As + (256 + tid) * 8;
  u16* lB0 = Bs + tid * 8;
  u16* lB1 = Bs + (256 + tid) * 8;

  const u16* pa[4];
  const u16* pb[4];
#pragma unroll
  for (int mi = 0; mi < 4; ++mi) {
    int ra = wm + mi * 16 + l16;
    pa[mi] = As + ra * 32 + (quad ^ ((ra >> 1) & 3)) * 8;
    int rb = wn + mi * 16 + l16;
    pb[mi] = Bs + rb * 32 + (quad ^ ((rb >> 1) & 3)) * 8;
  }

  for (int k0 = 0; k0 < K; k0 += 32) {
    async16(gA0 + k0, lA0);
    async16(gA1 + k0, lA1);
    async16(gB0 + k0, lB0);
    async16(gB1 + k0, lB1);
    __syncthreads();
    ushx8 af[4], bf[4];
#pragma unroll
    for (int i = 0; i < 4; ++i) {
      af[i] = *(const ushx8*)pa[i];
      bf[i] = *(const ushx8*)pb[i];
    }
#pragma unroll
    for (int mi = 0; mi < 4; ++mi)
#pragma unroll
      for (int ni = 0; ni < 4; ++ni)
        acc[mi][ni] = mfma_bf16(af[mi], bf[ni], acc[mi][ni]);
    __syncthreads();
  }

  if constexpr (QKV) {
    if (n0 < 2 * Cn) {
      const float sc = (n0 < Cn) ? SLOG2E : 1.f;
#pragma unroll
      for (int mi = 0; mi < 4; ++mi) {
#pragma unroll
        for (int ni = 0; ni < 4; ++ni) {
          int col = n0 + wn + ni * 16 + l16;
#pragma unroll
          for (int i = 0; i < 4; ++i) {
            int row = m0 + wm + mi * 16 + quad * 4 + i;
            ((u16*)Cout)[(size_t)row * QKS + col] = f2bf(acc[mi][ni][i] * sc);
          }
        }
      }
    } else {
#pragma unroll
      for (int mi = 0; mi < 4; ++mi) {
#pragma unroll
        for (int ni = 0; ni < 4; ++ni) {
          int colV = n0 + wn + ni * 16 + l16 - 2 * Cn;
          int hh = colV >> 6, dd = colV & 63;
          int row0 = m0 + wm + mi * 16 + quad * 4;
          int bb = row0 >> 10, tt = row0 & 1023;
          unsigned int lo = (unsigned int)f2bf(acc[mi][ni][0]) |
                            ((unsigned int)f2bf(acc[mi][ni][1]) << 16);
          unsigned int hi = (unsigned int)f2bf(acc[mi][ni][2]) |
                            ((unsigned int)f2bf(acc[mi][ni][3]) << 16);
          uint2 pk = {lo, hi};
          *(uint2*)&vt[((size_t)(bb * Hn + hh) * Dn + dd) * Tn + tt] = pk;
        }
      }
    }
  } else {
#pragma unroll
    for (int mi = 0; mi < 4; ++mi) {
#pragma unroll
      for (int ni = 0; ni < 4; ++ni) {
        int col = n0 + wn + ni * 16 + l16;
        float bv = bias[col];
#pragma unroll
        for (int i = 0; i < 4; ++i) {
          int row = m0 + wm + mi * 16 + quad * 4 + i;
          ((float*)Cout)[(size_t)row * N + col] = acc[mi][ni][i] + bv;
        }
      }
    }
  }
}

// ---------------- flash attention v5 ----------------
// 512 blocks (4,16,8) x 512 threads (8 waves). Block j does 128-row q-tiles
// j and 7-j (18 kv-tiles total — perfectly balanced, 2 blocks/CU = 16 waves/CU,
// no tail). Wave wv owns q rows [wv*16, wv*16+16) of the tile. Per wave exactly
// one diagonal kv-tile (tdiag = q0w>>6): earlier tiles unmasked, later skipped.
// Double-buffered async K/V^T staging; DPP reductions; raw v_exp_f32;
// per-lane l partials reduced once per phase. QK stride 2048, Q pre-scaled.
__global__ __launch_bounds__(512, 4) void attn_kernel(
    const u16* __restrict__ qk, const u16* __restrict__ vt,
    u16* __restrict__ out) {
  const int j = blockIdx.x, h = blockIdx.y, b = blockIdx.z;
  const int tid = threadIdx.x;
  const int lane = tid & 63;
  const int wv = tid >> 6;           // 0..7
  const int quad = lane >> 4;
  const int l16 = lane & 15;

  __shared__ alignas(16) u16 Ks[2][64 * 64];   // [buf][kv][d] XOR-swizzled
  __shared__ alignas(16) u16 Vts[2][64 * 64];  // [buf][d][kv] XOR-swizzled
  __shared__ alignas(16) u16 Ps[8][16 * 72];   // per-wave P

  const u16* qb = qk + (size_t)b * Tn * QKS + h * Dn;
  const u16* kb = qk + (size_t)b * Tn * QKS + Cn + h * Dn;
  const u16* vtb = vt + (size_t)(b * Hn + h) * Dn * Tn;

  const int srow = tid >> 3;  // 0..63
  const int scc = tid & 7;
  const int sgc = scc ^ (srow & 7);
  u16* pswv = Ps[wv];

#pragma unroll 1
  for (int ph = 0; ph < 2; ++ph) {
    const int qt = ph ? (7 - j) : j;
    const int q0w = qt * 128 + wv * 16;   // this wave's first q row
    const int ntiles = 2 * qt + 2;
    const int tdiag = q0w >> 6;           // in-phase diagonal tile index

    // Q fragments (A-operand: m=l16, k=quad*8+jj); already scaled by SLOG2E
    ushx8 qf[2];
    {
      const u16* qp = qb + (size_t)(q0w + l16) * QKS + quad * 8;
      qf[0] = *(const ushx8*)qp;
      qf[1] = *(const ushx8*)(qp + 32);
    }

    f32x4 o[4];
#pragma unroll
    for (int nt = 0; nt < 4; ++nt) o[nt] = (f32x4){0.f, 0.f, 0.f, 0.f};
    float mrow[4], lrow[4];
#pragma unroll
    for (int i = 0; i < 4; ++i) { mrow[i] = -__builtin_inff(); lrow[i] = 0.f; }

    __syncthreads();  // previous phase's compute done before overwriting buf0

    // prefetch tile 0 -> buf 0 (one 16B DMA per thread per buffer)
    async16(kb + (size_t)srow * QKS + sgc * 8, Ks[0] + tid * 8);
    async16(vtb + (size_t)srow * Tn + sgc * 8, Vts[0] + tid * 8);

#pragma unroll 1
    for (int t = 0; t < ntiles; ++t) {
      const int kv0 = t * 64;
      const int bi = t & 1;
      __syncthreads();  // drains DMA for buf[bi]; all waves done with buf[bi^1]

      if (t + 1 < ntiles) {
        const int nkv0 = kv0 + 64;
        async16(kb + (size_t)(nkv0 + srow) * QKS + sgc * 8, Ks[bi ^ 1] + tid * 8);
        async16(vtb + (size_t)srow * Tn + nkv0 + sgc * 8, Vts[bi ^ 1] + tid * 8);
      }

      if (t > tdiag) continue;   // fully-masked for this wave (wave-uniform)

      // S = Q K^T (already log2-scaled via Q)
      const u16* ks = Ks[bi];
      const u16* vs = Vts[bi];
      f32x4 s[4];
#pragma unroll
      for (int nt = 0; nt < 4; ++nt) s[nt] = (f32x4){0.f, 0.f, 0.f, 0.f};
#pragma unroll
      for (int nt = 0; nt < 4; ++nt) {
        const int rb = nt * 16 + l16;
        ushx8 b0 = *(const ushx8*)(ks + rb * 64 + (quad ^ (rb & 7)) * 8);
        ushx8 b1 = *(const ushx8*)(ks + rb * 64 + ((quad + 4) ^ (rb & 7)) * 8);
        s[nt] = mfma_bf16(qf[0], b0, s[nt]);
        s[nt] = mfma_bf16(qf[1], b1, s[nt]);
      }

      // online softmax; mask only on the wave's single diagonal tile
      if (t == tdiag) {
#pragma unroll
        for (int i = 0; i < 4; ++i) {
          const int qr = q0w + quad * 4 + i;
          float vv[4];
          float rmax = -__builtin_inff();
#pragma unroll
          for (int nt = 0; nt < 4; ++nt) {
            float v = s[nt][i];
            if ((kv0 + nt * 16 + l16) > qr) v = -__builtin_inff();
            vv[nt] = v;
            rmax = fmaxf(rmax, v);
          }
          rmax = red16max(rmax);
          const float mnew = fmaxf(mrow[i], rmax);
          const float al = __builtin_amdgcn_exp2f(mrow[i] - mnew);
          mrow[i] = mnew;
          float rsum = 0.f;
#pragma unroll
          for (int nt = 0; nt < 4; ++nt) {
            float p = __builtin_amdgcn_exp2f(vv[nt] - mnew);
            rsum += p;
            pswv[(quad * 4 + i) * 72 + nt * 16 + l16] = f2bf_rna(p);
          }
          lrow[i] = lrow[i] * al + rsum;   // per-lane partial; reduced at end
#pragma unroll
          for (int nt = 0; nt < 4; ++nt) o[nt][i] *= al;
        }
      } else {
#pragma unroll
        for (int i = 0; i < 4; ++i) {
          float rmax = fmaxf(fmaxf(s[0][i], s[1][i]), fmaxf(s[2][i], s[3][i]));
          rmax = red16max(rmax);
          const float mnew = fmaxf(mrow[i], rmax);
          const float al = __builtin_amdgcn_exp2f(mrow[i] - mnew);
          mrow[i] = mnew;
          float rsum = 0.f;
#pragma unroll
          for (int nt = 0; nt < 4; ++nt) {
            float p = __builtin_amdgcn_exp2f(s[nt][i] - mnew);
            rsum += p;
            pswv[(quad * 4 + i) * 72 + nt * 16 + l16] = f2bf_rna(p);
          }
          lrow[i] = lrow[i] * al + rsum;
#pragma unroll
          for (int nt = 0; nt < 4; ++nt) o[nt][i] *= al;
        }
      }

      // P A-fragments from wave-local LDS (DS in-order per wave, no barrier)
      ushx8 pf0, pf1;
      {
        const u16* pp = pswv + l16 * 72 + quad * 8;
        pf0 = *(const ushx8*)pp;
        pf1 = *(const ushx8*)(pp + 32);
      }

      // O += P V
#pragma unroll
      for (int nt = 0; nt < 4; ++nt) {
        const int rb = nt * 16 + l16;
        ushx8 v0 = *(const ushx8*)(vs + rb * 64 + (quad ^ (rb & 7)) * 8);
        ushx8 v1 = *(const ushx8*)(vs + rb * 64 + ((quad + 4) ^ (rb & 7)) * 8);
        o[nt] = mfma_bf16(pf0, v0, o[nt]);
        o[nt] = mfma_bf16(pf1, v1, o[nt]);
      }
    }

    // O/l (16-lane l reduction deferred to here), write y_attn bf16
#pragma unroll
    for (int i = 0; i < 4; ++i) {
      const float inv = 1.f / red16sum(lrow[i]);
      const int trow = q0w + quad * 4 + i;
      u16* op = out + ((size_t)(b * Tn + trow)) * Cn + h * Dn + l16;
#pragma unroll
      for (int nt = 0; nt < 4; ++nt) op[nt * 16] = f2bf(o[nt][i] * inv);
    }
  }
}

// ---------------- launch ----------------
extern "C" void kernel_launch(void* const* d_in, const int* in_sizes, int n_in,
                              void* d_out, int out_size, void* d_ws, size_t ws_size,
                              hipStream_t stream) {
  const float* x = (const float*)d_in[0];
  const float* w_qkv = (const float*)d_in[1];
  const float* w_proj = (const float*)d_in[2];
  const float* b_proj = (const float*)d_in[3];
  float* out = (float*)d_out;
  char* ws = (char*)d_ws;

  u16* xb     = (u16*)(ws);                 // 16 MiB @ 0
  u16* wqkvb  = (u16*)(ws + 16777216);      //  6 MiB @ 16
  u16* wprojb = (u16*)(ws + 23068672);      //  2 MiB @ 22
  u16* qkb    = (u16*)(ws + 25165824);      // 32 MiB @ 24  (packed QK, stride 2048)
  u16* vtb    = (u16*)(ws + 58720256);      // 16 MiB @ 56
  u16* yb     = (u16*)(ws + 75497472);      // 16 MiB @ 72  (ends 88 MiB)

  cast3_kernel<<<12288, 256, 0, stream>>>(x, xb, 2097152,
                                          w_qkv, wqkvb, 786432,
                                          w_proj, wprojb, 262144);

  gemm256_qkv<<<GQKV_BLOCKS, 512, 0, stream>>>(xb, wqkvb, qkb, vtb);

  attn_kernel<<<dim3(4, Hn, Bn), 512, 0, stream>>>(qkb, vtb, yb);

  gemm_bt<0><<<dim3(Mn / 128, Cn / 128), 256, 0, stream>>>(
      yb, wprojb, (void*)out, nullptr, b_proj, Cn, Cn);
}

// Round 2
// 230.528 us; speedup vs baseline: 1.0325x; 1.0325x over previous
//
#include <hip/hip_runtime.h>
#include <stdint.h>

// MHA forward, B=8 T=1024 C=1024 H=16 D=64.
// cast3 -> QKV GEMM (256x256 8-phase; REBALANCED: 1 region-stage/phase,
// uniform vmcnt(8) at every even phase => 4-phase stage->confirm gap;
// XCD chunk map 4m x 12n per XCD so A chunk [2 MiB] fits XCD L2;
// writes packed QK [stride 2048, Q pre-scaled] + V^T directly)
// -> flash attention (512-thr blocks, 128-row q-tile pairs, peeled causal mask,
// deferred l-reduction) -> proj GEMM (128x128 structure, +bias, fp32).
// 4 launches.

#define Bn 8
#define Tn 1024
#define Cn 1024
#define Hn 16
#define Dn 64
#define Mn (Bn * Tn)      // 8192
#define NQKV (3 * Cn)     // 3072
#define QKS 2048          // packed QK row stride
#define NTILE 16          // K / 64 for the 256^2 GEMM
#define GQKV_BLOCKS 384   // (8192/256) * (3072/256)

typedef unsigned short u16;
typedef float f32x4 __attribute__((ext_vector_type(4)));
typedef __bf16 bf16x8 __attribute__((ext_vector_type(8)));
typedef unsigned short ushx8 __attribute__((ext_vector_type(8)));
typedef unsigned short ushx4 __attribute__((ext_vector_type(4)));

__device__ __forceinline__ u16 f2bf(float f) {
  unsigned int u = __float_as_uint(f);
  u += 0x7fffu + ((u >> 16) & 1u);   // RTN-even
  return (u16)(u >> 16);
}
__device__ __forceinline__ u16 f2bf_rna(float f) {
  return (u16)((__float_as_uint(f) + 0x8000u) >> 16);
}

__device__ __forceinline__ f32x4 mfma_bf16(ushx8 a, ushx8 b, f32x4 c) {
  return __builtin_amdgcn_mfma_f32_16x16x32_bf16(
      __builtin_bit_cast(bf16x8, a), __builtin_bit_cast(bf16x8, b), c, 0, 0, 0);
}

// async global->LDS, 16B per lane; LDS dest = wave-uniform base + lane*16 (m104)
__device__ __forceinline__ void async16(const u16* g, u16* l) {
  __builtin_amdgcn_global_load_lds(
      (__attribute__((address_space(1))) void*)(void*)g,
      (__attribute__((address_space(3))) void*)l, 16, 0, 0);
}

// ---- DPP 16-lane butterfly reductions (VALU-rate, no LDS pipe) ----
template <int CTRL>
__device__ __forceinline__ float dppmov(float v) {
  return __builtin_bit_cast(float, __builtin_amdgcn_update_dpp(
      0, __builtin_bit_cast(int, v), CTRL, 0xf, 0xf, true));
}
__device__ __forceinline__ float red16max(float v) {
  v = fmaxf(v, dppmov<0xB1>(v));
  v = fmaxf(v, dppmov<0x4E>(v));
  v = fmaxf(v, dppmov<0x141>(v));
  v = fmaxf(v, dppmov<0x140>(v));
  return v;
}
__device__ __forceinline__ float red16sum(float v) {
  v += dppmov<0xB1>(v);
  v += dppmov<0x4E>(v);
  v += dppmov<0x141>(v);
  v += dppmov<0x140>(v);
  return v;
}

// ---------------- fused cast fp32 -> bf16 (3 tensors, 1 launch) ----------------
__global__ void cast3_kernel(const float* __restrict__ a, u16* __restrict__ oa, int na4,
                             const float* __restrict__ b, u16* __restrict__ ob, int nb4,
                             const float* __restrict__ c, u16* __restrict__ oc, int nc4) {
  int i = blockIdx.x * blockDim.x + threadIdx.x;
  const float* in;
  u16* out;
  if (i < na4) { in = a; out = oa; }
  else if (i < na4 + nb4) { in = b; out = ob; i -= na4; }
  else if (i < na4 + nb4 + nc4) { in = c; out = oc; i -= na4 + nb4; }
  else return;
  float4 v = ((const float4*)in)[i];
  ushx4 o = { f2bf(v.x), f2bf(v.y), f2bf(v.z), f2bf(v.w) };
  ((ushx4*)out)[i] = o;
}

#define SLOG2E 0.18033688011112042f

// ---------------- QKV GEMM: 256x256 tile, BK=64, 8-phase counted-vmcnt ----------------
// 512 threads = 8 waves (2 Mx4 N); per-wave 128x64 output = acc[8][4].
// LDS 128 KiB: A at 0, B at +32768 (u16), each [dbuf][khalf][256 rows][32 k] with
// chunk swizzle p = q ^ ((row>>1)&3) (conflict-free). Half-region (16 KB) staged
// by one stage() = 2 async16/thread, linear dest, pre-swizzled global source.
//
// Stage schedule (iter computes tiles t=2it [buf0], t+1 [buf1]; 2 loads/phase):
//   P1: A(t+1).k1 -> buf1.kk1      P2: B(t+1).k1 -> buf1.kk1 ; vmcnt(8)
//   P3: A(t+2).k0 -> buf0.kk0      P4: B(t+2).k0 -> buf0.kk0 ; vmcnt(8)
//   P5: A(t+2).k1 -> buf0.kk1      P6: B(t+2).k1 -> buf0.kk1 ; vmcnt(8)
//   P7: A(t+3).k0 -> buf1.kk0      P8: B(t+3).k0 -> buf1.kk0 ; vmcnt(8)
// Invariants (hand-verified, incl. prologue + clamped tail):
//   * every restage lands 1 phase after its slot's last ds_read (closing barrier
//     of that phase orders it);
//   * every read's staging is confirmed by the vmcnt(8)+barrier exactly 4 phases
//     (8 younger loads) after its last issue -> ~700-900cy latency cover;
//   * loop boundary: 8 outstanding = (t+2).k1 [P5/P6] + (t+3).k0 [P7/P8].
// Compute: P1:buf0 kk0 mg0, P2:kk0 mg1, P3:kk1 mg0, P4:kk1 mg1, P5-P8 same buf1.
__global__ __launch_bounds__(512, 2) void gemm256_qkv(
    const u16* __restrict__ A, const u16* __restrict__ Bw,
    u16* __restrict__ qk, u16* __restrict__ vt) {
  __shared__ alignas(16) u16 lds[65536];  // 128 KiB

  const int tid = threadIdx.x;
  const int lane = tid & 63;
  const int wv = tid >> 6;       // 0..7
  const int quad = lane >> 4;
  const int l16 = lane & 15;
  const int wr = wv >> 2;        // 0..1
  const int wc = wv & 3;         // 0..3

  // XCD chunk map: xcd = bid&7 owns m-tiles [xcd*4, xcd*4+4) x all 12 n-tiles,
  // m-fastest. Per-XCD A footprint = 4*512KB = 2 MiB (fits 4 MiB L2);
  // each B panel reused by 4 consecutive blocks. Bijective: 8*4*12 = 384.
  const int xcd = blockIdx.x & 7;
  const int loc = blockIdx.x >> 3;          // 0..47
  const int m0 = (xcd * 4 + (loc & 3)) * 256;
  const int n0 = (loc >> 2) * 256;

  const u16* gA = A + (size_t)m0 * Cn;
  const u16* gB = Bw + (size_t)n0 * Cn;

  // staging source offsets: chunk c = l*512+tid -> row c>>2, stored chunk c&3,
  // logical k-chunk q = (c&3) ^ ((row>>1)&3)  (inverse == same XOR)
  const int r0s = tid >> 2;
  const int q0s = (tid & 3) ^ ((r0s >> 1) & 3);
  const int c1s = 512 + tid;
  const int r1s = c1s >> 2;
  const int q1s = (c1s & 3) ^ ((r1s >> 1) & 3);
  const int so0 = r0s * Cn + q0s * 8;
  const int so1 = r1s * Cn + q1s * 8;

  auto stage = [&](int region, int buf, int kk, const u16* gbase, int kt) {
    u16* dst = lds + region + (buf * 2 + kk) * 8192 + tid * 8;
    const u16* src = gbase + kt * 64 + kk * 32;
    async16(src + so0, dst);
    async16(src + so1, dst + 4096);
  };

  // fragment read offsets (u16, within one [256][32] half-region)
  const int sread = (quad ^ ((l16 >> 1) & 3)) * 8;
  const int aoff = (wr * 128 + l16) * 32 + sread;           // + mg*2048 + mi*512
  const int boff = 32768 + (wc * 64 + l16) * 32 + sread;    // + ni*512

  f32x4 acc[8][4];
#pragma unroll
  for (int i = 0; i < 8; ++i)
#pragma unroll
    for (int j = 0; j < 4; ++j) acc[i][j] = (f32x4){0.f, 0.f, 0.f, 0.f};
  ushx8 af[4], bfr[4];

  // prologue: t0.k0, t0.k1, t1.k0 (12 loads); vmcnt(8) confirms t0.k0 only —
  // t0.k1 confirmed at end-P2, t1.k0 at end-P4 (4-phase gaps preserved).
  stage(0, 0, 0, gA, 0);      stage(32768, 0, 0, gB, 0);
  stage(0, 0, 1, gA, 0);      stage(32768, 0, 1, gB, 0);
  stage(0, 1, 0, gA, 1);      stage(32768, 1, 0, gB, 1);
  asm volatile("s_waitcnt vmcnt(8)" ::: "memory");
  __builtin_amdgcn_s_barrier();
  asm volatile("" ::: "memory");

#define PH(buf, kk, mg, LOADB, DOVM, ...)                                      \
  {                                                                            \
    const u16* hb_ = lds + ((buf) * 2 + (kk)) * 8192;                          \
    const u16* ab_ = hb_ + aoff + (mg) * 2048;                                 \
    af[0] = *(const ushx8*)(ab_);                                              \
    af[1] = *(const ushx8*)(ab_ + 512);                                        \
    af[2] = *(const ushx8*)(ab_ + 1024);                                       \
    af[3] = *(const ushx8*)(ab_ + 1536);                                       \
    if (LOADB) {                                                               \
      const u16* bb_ = hb_ + boff;                                             \
      bfr[0] = *(const ushx8*)(bb_);                                           \
      bfr[1] = *(const ushx8*)(bb_ + 512);                                     \
      bfr[2] = *(const ushx8*)(bb_ + 1024);                                    \
      bfr[3] = *(const ushx8*)(bb_ + 1536);                                    \
    }                                                                          \
    __VA_ARGS__;                                                               \
    asm volatile("" ::: "memory");                                             \
    __builtin_amdgcn_s_barrier();                                              \
    asm volatile("s_waitcnt lgkmcnt(0)" ::: "memory");                         \
    __builtin_amdgcn_s_setprio(1);                                             \
    _Pragma("unroll") for (int mi_ = 0; mi_ < 4; ++mi_) {                      \
      _Pragma("unroll") for (int ni_ = 0; ni_ < 4; ++ni_) {                    \
        acc[(mg) * 4 + mi_][ni_] =                                             \
            mfma_bf16(af[mi_], bfr[ni_], acc[(mg) * 4 + mi_][ni_]);            \
      }                                                                        \
    }                                                                          \
    __builtin_amdgcn_s_setprio(0);                                             \
    if (DOVM) asm volatile("s_waitcnt vmcnt(8)" ::: "memory");                 \
    asm volatile("" ::: "memory");                                             \
    __builtin_amdgcn_s_barrier();                                              \
    asm volatile("" ::: "memory");                                             \
  }

#pragma unroll 1
  for (int it = 0; it < 8; ++it) {
    const int t = it * 2;
    const int ktp1 = t + 1;
    const int kt2 = (t + 2 < NTILE) ? t + 2 : NTILE - 1;  // clamp: uniform vmcnt math
    const int kt3 = (t + 3 < NTILE) ? t + 3 : NTILE - 1;
    PH(0, 0, 0, 1, 0, stage(0,     1, 1, gA, ktp1))   // P1: A(t+1).k1
    PH(0, 0, 1, 0, 1, stage(32768, 1, 1, gB, ktp1))   // P2: B(t+1).k1 ; vmcnt(8)
    PH(0, 1, 0, 1, 0, stage(0,     0, 0, gA, kt2))    // P3: A(t+2).k0
    PH(0, 1, 1, 0, 1, stage(32768, 0, 0, gB, kt2))    // P4: B(t+2).k0 ; vmcnt(8)
    PH(1, 0, 0, 1, 0, stage(0,     0, 1, gA, kt2))    // P5: A(t+2).k1
    PH(1, 0, 1, 0, 1, stage(32768, 0, 1, gB, kt2))    // P6: B(t+2).k1 ; vmcnt(8)
    PH(1, 1, 0, 1, 0, stage(0,     1, 0, gA, kt3))    // P7: A(t+3).k0
    PH(1, 1, 1, 0, 1, stage(32768, 1, 0, gB, kt3))    // P8: B(t+3).k0 ; vmcnt(8)
  }
#undef PH
  asm volatile("s_waitcnt vmcnt(0)" ::: "memory");

  // epilogue: packed QK (Q pre-scaled) or V^T
  if (n0 < 2 * Cn) {
    const float sc = (n0 < Cn) ? SLOG2E : 1.f;
#pragma unroll
    for (int mi = 0; mi < 8; ++mi) {
#pragma unroll
      for (int ni = 0; ni < 4; ++ni) {
        const int col = n0 + wc * 64 + ni * 16 + l16;
        const int row = m0 + wr * 128 + mi * 16 + quad * 4;
#pragma unroll
        for (int i = 0; i < 4; ++i)
          qk[(size_t)(row + i) * QKS + col] = f2bf(acc[mi][ni][i] * sc);
      }
    }
  } else {
#pragma unroll
    for (int mi = 0; mi < 8; ++mi) {
#pragma unroll
      for (int ni = 0; ni < 4; ++ni) {
        const int colV = n0 - 2 * Cn + wc * 64 + ni * 16 + l16;  // 0..1023
        const int hh = colV >> 6, dd = colV & 63;
        const int row0 = m0 + wr * 128 + mi * 16 + quad * 4;
        const int bb = row0 >> 10, tt = row0 & 1023;
        unsigned int lo = (unsigned int)f2bf(acc[mi][ni][0]) |
                          ((unsigned int)f2bf(acc[mi][ni][1]) << 16);
        unsigned int hi = (unsigned int)f2bf(acc[mi][ni][2]) |
                          ((unsigned int)f2bf(acc[mi][ni][3]) << 16);
        uint2 pk = {lo, hi};
        *(uint2*)&vt[((size_t)(bb * Hn + hh) * Dn + dd) * Tn + tt] = pk;
      }
    }
  }
}

// ---------------- GEMM (round-6 structure; used for proj only) ----------------
template <int QKV>
__global__ __launch_bounds__(256, 4) void gemm_bt(
    const u16* __restrict__ A, const u16* __restrict__ Bw,
    void* __restrict__ Cout, u16* __restrict__ vt,
    const float* __restrict__ bias, int N, int K) {
  __shared__ alignas(16) u16 As[128 * 32];
  __shared__ alignas(16) u16 Bs[128 * 32];

  const int tid = threadIdx.x;
  const int lane = tid & 63;
  const int wv = tid >> 6;
  const int quad = lane >> 4;
  const int l16 = lane & 15;
  const int m0 = blockIdx.x * 128;
  const int n0 = blockIdx.y * 128;
  const int wm = (wv >> 1) * 64;
  const int wn = (wv & 1) * 64;

  f32x4 acc[4][4];
#pragma unroll
  for (int i = 0; i < 4; ++i)
#pragma unroll
    for (int j = 0; j < 4; ++j) acc[i][j] = (f32x4){0.f, 0.f, 0.f, 0.f};

  const int r0 = tid >> 2;
  const int cc0 = tid & 3;
  const int gkc0 = cc0 ^ ((r0 >> 1) & 3);
  const int r1 = r0 + 64;
  const int gkc1 = cc0 ^ ((r1 >> 1) & 3);
  const u16* gA0 = A + (size_t)(m0 + r0) * K + gkc0 * 8;
  const u16* gA1 = A + (size_t)(m0 + r1) * K + gkc1 * 8;
  const u16* gB0 = Bw + (size_t)(n0 + r0) * K + gkc0 * 8;
  const u16* gB1 = Bw + (size_t)(n0 + r1) * K + gkc1 * 8;
  u16* lA0 = As + tid * 8;
  u16* lA1 = As + (256 + tid) * 8;
  u16* lB0 = Bs + tid * 8;
  u16* lB1 = Bs + (256 + tid) * 8;

  const u16* pa[4];
  const u16* pb[4];
#pragma unroll
  for (int mi = 0; mi < 4; ++mi) {
    int ra = wm + mi * 16 + l16;
    pa[mi] = As + ra * 32 + (quad ^ ((ra >> 1) & 3)) * 8;
    int rb = wn + mi * 16 + l16;
    pb[mi] = Bs + rb * 32 + (quad ^ ((rb >> 1) & 3)) * 8;
  }

  for (int k0 = 0; k0 < K; k0 += 32) {
    async16(gA0 + k0, lA0);
    async16(gA1 + k0, lA1);
    async16(gB0 + k0, lB0);
    async16(gB1 + k0, lB1);
    __syncthreads();
    ushx8 af[4], bf[4];
#pragma unroll
    for (int i = 0; i < 4; ++i) {
      af[i] = *(const ushx8*)pa[i];
      bf[i] = *(const ushx8*)pb[i];
    }
#pragma unroll
    for (int mi = 0; mi < 4; ++mi)
#pragma unroll
      for (int ni = 0; ni < 4; ++ni)
        acc[mi][ni] = mfma_bf16(af[mi], bf[ni], acc[mi][ni]);
    __syncthreads();
  }

  if constexpr (QKV) {
    if (n0 < 2 * Cn) {
      const float sc = (n0 < Cn) ? SLOG2E : 1.f;
#pragma unroll
      for (int mi = 0; mi < 4; ++mi) {
#pragma unroll
        for (int ni = 0; ni < 4; ++ni) {
          int col = n0 + wn + ni * 16 + l16;
#pragma unroll
          for (int i = 0; i < 4; ++i) {
            int row = m0 + wm + mi * 16 + quad * 4 + i;
            ((u16*)Cout)[(size_t)row * QKS + col] = f2bf(acc[mi][ni][i] * sc);
          }
        }
      }
    } else {
#pragma unroll
      for (int mi = 0; mi < 4; ++mi) {
#pragma unroll
        for (int ni = 0; ni < 4; ++ni) {
          int colV = n0 + wn + ni * 16 + l16 - 2 * Cn;
          int hh = colV >> 6, dd = colV & 63;
          int row0 = m0 + wm + mi * 16 + quad * 4;
          int bb = row0 >> 10, tt = row0 & 1023;
          unsigned int lo = (unsigned int)f2bf(acc[mi][ni][0]) |
                            ((unsigned int)f2bf(acc[mi][ni][1]) << 16);
          unsigned int hi = (unsigned int)f2bf(acc[mi][ni][2]) |
                            ((unsigned int)f2bf(acc[mi][ni][3]) << 16);
          uint2 pk = {lo, hi};
          *(uint2*)&vt[((size_t)(bb * Hn + hh) * Dn + dd) * Tn + tt] = pk;
        }
      }
    }
  } else {
#pragma unroll
    for (int mi = 0; mi < 4; ++mi) {
#pragma unroll
      for (int ni = 0; ni < 4; ++ni) {
        int col = n0 + wn + ni * 16 + l16;
        float bv = bias[col];
#pragma unroll
        for (int i = 0; i < 4; ++i) {
          int row = m0 + wm + mi * 16 + quad * 4 + i;
          ((float*)Cout)[(size_t)row * N + col] = acc[mi][ni][i] + bv;
        }
      }
    }
  }
}

// ---------------- flash attention v5 ----------------
__global__ __launch_bounds__(512, 4) void attn_kernel(
    const u16* __restrict__ qk, const u16* __restrict__ vt,
    u16* __restrict__ out) {
  const int j = blockIdx.x, h = blockIdx.y, b = blockIdx.z;
  const int tid = threadIdx.x;
  const int lane = tid & 63;
  const int wv = tid >> 6;           // 0..7
  const int quad = lane >> 4;
  const int l16 = lane & 15;

  __shared__ alignas(16) u16 Ks[2][64 * 64];   // [buf][kv][d] XOR-swizzled
  __shared__ alignas(16) u16 Vts[2][64 * 64];  // [buf][d][kv] XOR-swizzled
  __shared__ alignas(16) u16 Ps[8][16 * 72];   // per-wave P

  const u16* qb = qk + (size_t)b * Tn * QKS + h * Dn;
  const u16* kb = qk + (size_t)b * Tn * QKS + Cn + h * Dn;
  const u16* vtb = vt + (size_t)(b * Hn + h) * Dn * Tn;

  const int srow = tid >> 3;  // 0..63
  const int scc = tid & 7;
  const int sgc = scc ^ (srow & 7);
  u16* pswv = Ps[wv];

#pragma unroll 1
  for (int ph = 0; ph < 2; ++ph) {
    const int qt = ph ? (7 - j) : j;
    const int q0w = qt * 128 + wv * 16;   // this wave's first q row
    const int ntiles = 2 * qt + 2;
    const int tdiag = q0w >> 6;           // in-phase diagonal tile index

    // Q fragments (A-operand: m=l16, k=quad*8+jj); already scaled by SLOG2E
    ushx8 qf[2];
    {
      const u16* qp = qb + (size_t)(q0w + l16) * QKS + quad * 8;
      qf[0] = *(const ushx8*)qp;
      qf[1] = *(const ushx8*)(qp + 32);
    }

    f32x4 o[4];
#pragma unroll
    for (int nt = 0; nt < 4; ++nt) o[nt] = (f32x4){0.f, 0.f, 0.f, 0.f};
    float mrow[4], lrow[4];
#pragma unroll
    for (int i = 0; i < 4; ++i) { mrow[i] = -__builtin_inff(); lrow[i] = 0.f; }

    __syncthreads();  // previous phase's compute done before overwriting buf0

    // prefetch tile 0 -> buf 0 (one 16B DMA per thread per buffer)
    async16(kb + (size_t)srow * QKS + sgc * 8, Ks[0] + tid * 8);
    async16(vtb + (size_t)srow * Tn + sgc * 8, Vts[0] + tid * 8);

#pragma unroll 1
    for (int t = 0; t < ntiles; ++t) {
      const int kv0 = t * 64;
      const int bi = t & 1;
      __syncthreads();  // drains DMA for buf[bi]; all waves done with buf[bi^1]

      if (t + 1 < ntiles) {
        const int nkv0 = kv0 + 64;
        async16(kb + (size_t)(nkv0 + srow) * QKS + sgc * 8, Ks[bi ^ 1] + tid * 8);
        async16(vtb + (size_t)srow * Tn + nkv0 + sgc * 8, Vts[bi ^ 1] + tid * 8);
      }

      if (t > tdiag) continue;   // fully-masked for this wave (wave-uniform)

      // S = Q K^T (already log2-scaled via Q)
      const u16* ks = Ks[bi];
      const u16* vs = Vts[bi];
      f32x4 s[4];
#pragma unroll
      for (int nt = 0; nt < 4; ++nt) s[nt] = (f32x4){0.f, 0.f, 0.f, 0.f};
#pragma unroll
      for (int nt = 0; nt < 4; ++nt) {
        const int rb = nt * 16 + l16;
        ushx8 b0 = *(const ushx8*)(ks + rb * 64 + (quad ^ (rb & 7)) * 8);
        ushx8 b1 = *(const ushx8*)(ks + rb * 64 + ((quad + 4) ^ (rb & 7)) * 8);
        s[nt] = mfma_bf16(qf[0], b0, s[nt]);
        s[nt] = mfma_bf16(qf[1], b1, s[nt]);
      }

      // online softmax; mask only on the wave's single diagonal tile
      if (t == tdiag) {
#pragma unroll
        for (int i = 0; i < 4; ++i) {
          const int qr = q0w + quad * 4 + i;
          float vv[4];
          float rmax = -__builtin_inff();
#pragma unroll
          for (int nt = 0; nt < 4; ++nt) {
            float v = s[nt][i];
            if ((kv0 + nt * 16 + l16) > qr) v = -__builtin_inff();
            vv[nt] = v;
            rmax = fmaxf(rmax, v);
          }
          rmax = red16max(rmax);
          const float mnew = fmaxf(mrow[i], rmax);
          const float al = __builtin_amdgcn_exp2f(mrow[i] - mnew);
          mrow[i] = mnew;
          float rsum = 0.f;
#pragma unroll
          for (int nt = 0; nt < 4; ++nt) {
            float p = __builtin_amdgcn_exp2f(vv[nt] - mnew);
            rsum += p;
            pswv[(quad * 4 + i) * 72 + nt * 16 + l16] = f2bf_rna(p);
          }
          lrow[i] = lrow[i] * al + rsum;   // per-lane partial; reduced at end
#pragma unroll
          for (int nt = 0; nt < 4; ++nt) o[nt][i] *= al;
        }
      } else {
#pragma unroll
        for (int i = 0; i < 4; ++i) {
          float rmax = fmaxf(fmaxf(s[0][i], s[1][i]), fmaxf(s[2][i], s[3][i]));
          rmax = red16max(rmax);
          const float mnew = fmaxf(mrow[i], rmax);
          const float al = __builtin_amdgcn_exp2f(mrow[i] - mnew);
          mrow[i] = mnew;
          float rsum = 0.f;
#pragma unroll
          for (int nt = 0; nt < 4; ++nt) {
            float p = __builtin_amdgcn_exp2f(s[nt][i] - mnew);
            rsum += p;
            pswv[(quad * 4 + i) * 72 + nt * 16 + l16] = f2bf_rna(p);
          }
          lrow[i] = lrow[i] * al + rsum;
#pragma unroll
          for (int nt = 0; nt < 4; ++nt) o[nt][i] *= al;
        }
      }

      // P A-fragments from wave-local LDS (DS in-order per wave, no barrier)
      ushx8 pf0, pf1;
      {
        const u16* pp = pswv + l16 * 72 + quad * 8;
        pf0 = *(const ushx8*)pp;
        pf1 = *(const ushx8*)(pp + 32);
      }

      // O += P V
#pragma unroll
      for (int nt = 0; nt < 4; ++nt) {
        const int rb = nt * 16 + l16;
        ushx8 v0 = *(const ushx8*)(vs + rb * 64 + (quad ^ (rb & 7)) * 8);
        ushx8 v1 = *(const ushx8*)(vs + rb * 64 + ((quad + 4) ^ (rb & 7)) * 8);
        o[nt] = mfma_bf16(pf0, v0, o[nt]);
        o[nt] = mfma_bf16(pf1, v1, o[nt]);
      }
    }

    // O/l (16-lane l reduction deferred to here), write y_attn bf16
#pragma unroll
    for (int i = 0; i < 4; ++i) {
      const float inv = 1.f / red16sum(lrow[i]);
      const int trow = q0w + quad * 4 + i;
      u16* op = out + ((size_t)(b * Tn + trow)) * Cn + h * Dn + l16;
#pragma unroll
      for (int nt = 0; nt < 4; ++nt) op[nt * 16] = f2bf(o[nt][i] * inv);
    }
  }
}

// ---------------- launch ----------------
extern "C" void kernel_launch(void* const* d_in, const int* in_sizes, int n_in,
                              void* d_out, int out_size, void* d_ws, size_t ws_size,
                              hipStream_t stream) {
  const float* x = (const float*)d_in[0];
  const float* w_qkv = (const float*)d_in[1];
  const float* w_proj = (const float*)d_in[2];
  const float* b_proj = (const float*)d_in[3];
  float* out = (float*)d_out;
  char* ws = (char*)d_ws;

  u16* xb     = (u16*)(ws);                 // 16 MiB @ 0
  u16* wqkvb  = (u16*)(ws + 16777216);      //  6 MiB @ 16
  u16* wprojb = (u16*)(ws + 23068672);      //  2 MiB @ 22
  u16* qkb    = (u16*)(ws + 25165824);      // 32 MiB @ 24  (packed QK, stride 2048)
  u16* vtb    = (u16*)(ws + 58720256);      // 16 MiB @ 56
  u16* yb     = (u16*)(ws + 75497472);      // 16 MiB @ 72  (ends 88 MiB)

  cast3_kernel<<<12288, 256, 0, stream>>>(x, xb, 2097152,
                                          w_qkv, wqkvb, 786432,
                                          w_proj, wprojb, 262144);

  gemm256_qkv<<<GQKV_BLOCKS, 512, 0, stream>>>(xb, wqkvb, qkb, vtb);

  attn_kernel<<<dim3(4, Hn, Bn), 512, 0, stream>>>(qkb, vtb, yb);

  gemm_bt<0><<<dim3(Mn / 128, Cn / 128), 256, 0, stream>>>(
      yb, wprojb, (void*)out, nullptr, b_proj, Cn, Cn);
}

// Round 3
// 219.826 us; speedup vs baseline: 1.0828x; 1.0487x over previous
//
#include <hip/hip_runtime.h>
#include <stdint.h>

// MHA forward, B=8 T=1024 C=1024 H=16 D=64.
// cast3 -> QKV GEMM (256x128-tile 8-phase uniform counted-vmcnt, 768 blocks =
// 3.0 exact rounds; writes packed QK [stride 2048, Q pre-scaled] + V^T)
// -> flash attention (512-thr blocks, 128-row q-tile pairs, peeled causal mask,
// deferred l-reduction) -> proj GEMM (same template, 256 blocks = 1.0 round,
// fp32 +bias). 4 launches.

#define Bn 8
#define Tn 1024
#define Cn 1024
#define Hn 16
#define Dn 64
#define Mn (Bn * Tn)      // 8192
#define NQKV (3 * Cn)     // 3072
#define QKS 2048          // packed QK row stride

typedef unsigned short u16;
typedef float f32x4 __attribute__((ext_vector_type(4)));
typedef __bf16 bf16x8 __attribute__((ext_vector_type(8)));
typedef unsigned short ushx8 __attribute__((ext_vector_type(8)));
typedef unsigned short ushx4 __attribute__((ext_vector_type(4)));

__device__ __forceinline__ u16 f2bf(float f) {
  unsigned int u = __float_as_uint(f);
  u += 0x7fffu + ((u >> 16) & 1u);   // RTN-even
  return (u16)(u >> 16);
}
__device__ __forceinline__ u16 f2bf_rna(float f) {
  return (u16)((__float_as_uint(f) + 0x8000u) >> 16);
}

__device__ __forceinline__ f32x4 mfma_bf16(ushx8 a, ushx8 b, f32x4 c) {
  return __builtin_amdgcn_mfma_f32_16x16x32_bf16(
      __builtin_bit_cast(bf16x8, a), __builtin_bit_cast(bf16x8, b), c, 0, 0, 0);
}

// async global->LDS, 16B per lane; LDS dest = wave-uniform base + lane*16 (m104)
__device__ __forceinline__ void async16(const u16* g, u16* l) {
  __builtin_amdgcn_global_load_lds(
      (__attribute__((address_space(1))) void*)(void*)g,
      (__attribute__((address_space(3))) void*)l, 16, 0, 0);
}

// ---- DPP 16-lane butterfly reductions (VALU-rate, no LDS pipe) ----
template <int CTRL>
__device__ __forceinline__ float dppmov(float v) {
  return __builtin_bit_cast(float, __builtin_amdgcn_update_dpp(
      0, __builtin_bit_cast(int, v), CTRL, 0xf, 0xf, true));
}
__device__ __forceinline__ float red16max(float v) {
  v = fmaxf(v, dppmov<0xB1>(v));
  v = fmaxf(v, dppmov<0x4E>(v));
  v = fmaxf(v, dppmov<0x141>(v));
  v = fmaxf(v, dppmov<0x140>(v));
  return v;
}
__device__ __forceinline__ float red16sum(float v) {
  v += dppmov<0xB1>(v);
  v += dppmov<0x4E>(v);
  v += dppmov<0x141>(v);
  v += dppmov<0x140>(v);
  return v;
}

// ---------------- fused cast fp32 -> bf16 (3 tensors, 1 launch) ----------------
__global__ void cast3_kernel(const float* __restrict__ a, u16* __restrict__ oa, int na4,
                             const float* __restrict__ b, u16* __restrict__ ob, int nb4,
                             const float* __restrict__ c, u16* __restrict__ oc, int nc4) {
  int i = blockIdx.x * blockDim.x + threadIdx.x;
  const float* in;
  u16* out;
  if (i < na4) { in = a; out = oa; }
  else if (i < na4 + nb4) { in = b; out = ob; i -= na4; }
  else if (i < na4 + nb4 + nc4) { in = c; out = oc; i -= na4 + nb4; }
  else return;
  float4 v = ((const float4*)in)[i];
  ushx4 o = { f2bf(v.x), f2bf(v.y), f2bf(v.z), f2bf(v.w) };
  ((ushx4*)out)[i] = o;
}

#define SLOG2E 0.18033688011112042f

// ---------------- GEMM: 256x128 tile, BK=64, uniform 8-phase counted-vmcnt ----------
// 512 threads = 8 waves (4 M x 2 N); per-wave 64x64 output = acc[4][4].
// LDS 96 KiB: A = 4 slots x [256][32] (8192 u16 each) at 0; B = 4 slots x
// [128][32] (4096 u16) at +32768. Slot s <-> (buf=s>>1, kk=s&1). Chunk swizzle
// p = q ^ ((row>>1)&3) (conflict-free, measured 0 in this family).
//
// Half-tiles h = 0..31 (tile = h>>1 of BK=64, kk = h&1); slot(h) = h&3.
// Phase p (0..31): read slot p&3 (data h=p); stage h' = min(p+3, 31) into slot
// (p+3)&3 (= slot read at p-1; its readers crossed the p-1 closing barrier, so
// the DMA cannot land on live data); barrier; lgkmcnt(0); 16 MFMA; vmcnt(6);
// barrier. vmcnt(6) at end of p confirms stages issued at <= p-2, i.e. phase
// p+1's data, with a 2-phase (~1400cy > 900cy HBM) issue->confirm gap.
// Tail (p>=29) clamps DATA to h=31, slot keeps rotating (targets never read).
// Prologue: stage h=0,1,2 (9 loads); vmcnt(6) confirms h0; barrier.
// MODE=1: cols [0,2048)->packed QK (Q cols pre-scaled); [2048,3072)->V^T.
// MODE=0: fp32 out + bias (N = Cn).
template <int MODE>
__global__ __launch_bounds__(512, 2) void gemm_8ph(
    const u16* __restrict__ A, const u16* __restrict__ Bw,
    void* __restrict__ Cout, u16* __restrict__ vt,
    const float* __restrict__ bias) {
  __shared__ alignas(16) u16 lds[49152];  // 96 KiB

  const int tid = threadIdx.x;
  const int lane = tid & 63;
  const int wv = tid >> 6;       // 0..7
  const int quad = lane >> 4;
  const int l16 = lane & 15;
  const int wr = wv >> 1;        // 0..3 (M)
  const int wc = wv & 1;         // 0..1 (N)

  // XCD chunk map: xcd = bid&7 owns 4 consecutive 256-row m-tiles x all
  // n-tiles, m-fastest (A chunk 2 MiB fits XCD L2; B panel reused 4x).
  // Bijective for grid = 8*4*nn (QKV nn=24 -> 768, proj nn=8 -> 256).
  const int xcd = blockIdx.x & 7;
  const int loc = blockIdx.x >> 3;
  const int m0 = (xcd * 4 + (loc & 3)) * 256;
  const int n0 = (loc >> 2) * 128;

  const u16* gA = A + (size_t)m0 * Cn;
  const u16* gB = Bw + (size_t)n0 * Cn;

  // staging source offsets: chunk c -> row c>>2, stored chunk c&3,
  // global k-chunk q = (c&3) ^ ((row>>1)&3)  (XOR is its own inverse)
  const int r0s = tid >> 2;
  const int q0s = (tid & 3) ^ ((r0s >> 1) & 3);
  const int c1s = 512 + tid;
  const int r1s = c1s >> 2;
  const int q1s = (c1s & 3) ^ ((r1s >> 1) & 3);
  const int so0 = r0s * Cn + q0s * 8;
  const int so1 = r1s * Cn + q1s * 8;

  // stage one A half [256][32] (2 loads) + one B half [128][32] (1 load)
  auto stageA = [&](int slot, int h) {
    u16* dst = lds + slot * 8192 + tid * 8;
    const u16* src = gA + (h >> 1) * 64 + (h & 1) * 32;
    async16(src + so0, dst);
    async16(src + so1, dst + 4096);
  };
  auto stageB = [&](int slot, int h) {
    u16* dst = lds + 32768 + slot * 4096 + tid * 8;
    const u16* src = gB + (h >> 1) * 64 + (h & 1) * 32;
    async16(src + so0, dst);
  };

  // fragment read offsets (u16, within one half-region)
  const int sread = (quad ^ ((l16 >> 1) & 3)) * 8;
  const int aoff = (wr * 64 + l16) * 32 + sread;            // + mi*512 + slot*8192
  const int boff = 32768 + (wc * 64 + l16) * 32 + sread;    // + ni*512 + slot*4096

  f32x4 acc[4][4];
#pragma unroll
  for (int i = 0; i < 4; ++i)
#pragma unroll
    for (int j = 0; j < 4; ++j) acc[i][j] = (f32x4){0.f, 0.f, 0.f, 0.f};
  ushx8 af[4], bfr[4];

  // prologue: h0,h1,h2 into slots 0,1,2 (9 loads); vmcnt(6) confirms h0
  stageA(0, 0); stageB(0, 0);
  stageA(1, 1); stageB(1, 1);
  stageA(2, 2); stageB(2, 2);
  asm volatile("s_waitcnt vmcnt(6)" ::: "memory");
  __builtin_amdgcn_s_barrier();
  asm volatile("" ::: "memory");

#define PH(slot, sslot, hd)                                                    \
  {                                                                            \
    const u16* ab_ = lds + (slot) * 8192 + aoff;                               \
    af[0] = *(const ushx8*)(ab_);                                              \
    af[1] = *(const ushx8*)(ab_ + 512);                                        \
    af[2] = *(const ushx8*)(ab_ + 1024);                                       \
    af[3] = *(const ushx8*)(ab_ + 1536);                                       \
    const u16* bb_ = lds + (slot) * 4096 + boff;                               \
    bfr[0] = *(const ushx8*)(bb_);                                             \
    bfr[1] = *(const ushx8*)(bb_ + 512);                                       \
    bfr[2] = *(const ushx8*)(bb_ + 1024);                                      \
    bfr[3] = *(const ushx8*)(bb_ + 1536);                                      \
    stageA((sslot), (hd));                                                     \
    stageB((sslot), (hd));                                                     \
    asm volatile("" ::: "memory");                                             \
    __builtin_amdgcn_s_barrier();                                              \
    asm volatile("s_waitcnt lgkmcnt(0)" ::: "memory");                         \
    __builtin_amdgcn_s_setprio(1);                                             \
    _Pragma("unroll") for (int mi_ = 0; mi_ < 4; ++mi_) {                      \
      _Pragma("unroll") for (int ni_ = 0; ni_ < 4; ++ni_) {                    \
        acc[mi_][ni_] = mfma_bf16(af[mi_], bfr[ni_], acc[mi_][ni_]);           \
      }                                                                        \
    }                                                                          \
    __builtin_amdgcn_s_setprio(0);                                             \
    asm volatile("s_waitcnt vmcnt(6)" ::: "memory");                           \
    asm volatile("" ::: "memory");                                             \
    __builtin_amdgcn_s_barrier();                                              \
    asm volatile("" ::: "memory");                                             \
  }

#pragma unroll 1
  for (int it = 0; it < 8; ++it) {
    const int p = it * 4;
    const int h0 = (p + 3 < 32) ? p + 3 : 31;
    const int h1 = (p + 4 < 32) ? p + 4 : 31;
    const int h2 = (p + 5 < 32) ? p + 5 : 31;
    const int h3 = (p + 6 < 32) ? p + 6 : 31;
    PH(0, 3, h0)
    PH(1, 0, h1)
    PH(2, 1, h2)
    PH(3, 2, h3)
  }
#undef PH
  asm volatile("s_waitcnt vmcnt(0)" ::: "memory");

  // epilogue
  if constexpr (MODE) {
    if (n0 < 2 * Cn) {
      const float sc = (n0 < Cn) ? SLOG2E : 1.f;
#pragma unroll
      for (int mi = 0; mi < 4; ++mi) {
#pragma unroll
        for (int ni = 0; ni < 4; ++ni) {
          const int col = n0 + wc * 64 + ni * 16 + l16;
          const int row = m0 + wr * 64 + mi * 16 + quad * 4;
#pragma unroll
          for (int i = 0; i < 4; ++i)
            ((u16*)Cout)[(size_t)(row + i) * QKS + col] = f2bf(acc[mi][ni][i] * sc);
        }
      }
    } else {
#pragma unroll
      for (int mi = 0; mi < 4; ++mi) {
#pragma unroll
        for (int ni = 0; ni < 4; ++ni) {
          const int colV = n0 - 2 * Cn + wc * 64 + ni * 16 + l16;  // 0..1023
          const int hh = colV >> 6, dd = colV & 63;
          const int row0 = m0 + wr * 64 + mi * 16 + quad * 4;
          const int bb = row0 >> 10, tt = row0 & 1023;
          unsigned int lo = (unsigned int)f2bf(acc[mi][ni][0]) |
                            ((unsigned int)f2bf(acc[mi][ni][1]) << 16);
          unsigned int hi = (unsigned int)f2bf(acc[mi][ni][2]) |
                            ((unsigned int)f2bf(acc[mi][ni][3]) << 16);
          uint2 pk = {lo, hi};
          *(uint2*)&vt[((size_t)(bb * Hn + hh) * Dn + dd) * Tn + tt] = pk;
        }
      }
    }
  } else {
#pragma unroll
    for (int mi = 0; mi < 4; ++mi) {
#pragma unroll
      for (int ni = 0; ni < 4; ++ni) {
        const int col = n0 + wc * 64 + ni * 16 + l16;
        const float bv = bias[col];
        const int row = m0 + wr * 64 + mi * 16 + quad * 4;
#pragma unroll
        for (int i = 0; i < 4; ++i)
          ((float*)Cout)[(size_t)(row + i) * Cn + col] = acc[mi][ni][i] + bv;
      }
    }
  }
}

// ---------------- flash attention v5 ----------------
// 512 blocks (4,16,8) x 512 threads (8 waves). Block j does 128-row q-tiles
// j and 7-j (18 kv-tiles total — balanced, 2 blocks/CU = 16 waves/CU).
// Wave wv owns q rows [wv*16, wv*16+16). Per wave one diagonal kv-tile.
// Double-buffered async K/V^T staging; DPP reductions; raw v_exp_f32;
// per-lane l partials reduced once per phase. QK stride 2048, Q pre-scaled.
__global__ __launch_bounds__(512, 4) void attn_kernel(
    const u16* __restrict__ qk, const u16* __restrict__ vt,
    u16* __restrict__ out) {
  const int j = blockIdx.x, h = blockIdx.y, b = blockIdx.z;
  const int tid = threadIdx.x;
  const int lane = tid & 63;
  const int wv = tid >> 6;           // 0..7
  const int quad = lane >> 4;
  const int l16 = lane & 15;

  __shared__ alignas(16) u16 Ks[2][64 * 64];   // [buf][kv][d] XOR-swizzled
  __shared__ alignas(16) u16 Vts[2][64 * 64];  // [buf][d][kv] XOR-swizzled
  __shared__ alignas(16) u16 Ps[8][16 * 72];   // per-wave P

  const u16* qb = qk + (size_t)b * Tn * QKS + h * Dn;
  const u16* kb = qk + (size_t)b * Tn * QKS + Cn + h * Dn;
  const u16* vtb = vt + (size_t)(b * Hn + h) * Dn * Tn;

  const int srow = tid >> 3;  // 0..63
  const int scc = tid & 7;
  const int sgc = scc ^ (srow & 7);
  u16* pswv = Ps[wv];

#pragma unroll 1
  for (int ph = 0; ph < 2; ++ph) {
    const int qt = ph ? (7 - j) : j;
    const int q0w = qt * 128 + wv * 16;   // this wave's first q row
    const int ntiles = 2 * qt + 2;
    const int tdiag = q0w >> 6;           // in-phase diagonal tile index

    // Q fragments (A-operand: m=l16, k=quad*8+jj); already scaled by SLOG2E
    ushx8 qf[2];
    {
      const u16* qp = qb + (size_t)(q0w + l16) * QKS + quad * 8;
      qf[0] = *(const ushx8*)qp;
      qf[1] = *(const ushx8*)(qp + 32);
    }

    f32x4 o[4];
#pragma unroll
    for (int nt = 0; nt < 4; ++nt) o[nt] = (f32x4){0.f, 0.f, 0.f, 0.f};
    float mrow[4], lrow[4];
#pragma unroll
    for (int i = 0; i < 4; ++i) { mrow[i] = -__builtin_inff(); lrow[i] = 0.f; }

    __syncthreads();  // previous phase's compute done before overwriting buf0

    // prefetch tile 0 -> buf 0 (one 16B DMA per thread per buffer)
    async16(kb + (size_t)srow * QKS + sgc * 8, Ks[0] + tid * 8);
    async16(vtb + (size_t)srow * Tn + sgc * 8, Vts[0] + tid * 8);

#pragma unroll 1
    for (int t = 0; t < ntiles; ++t) {
      const int kv0 = t * 64;
      const int bi = t & 1;
      __syncthreads();  // drains DMA for buf[bi]; all waves done with buf[bi^1]

      if (t + 1 < ntiles) {
        const int nkv0 = kv0 + 64;
        async16(kb + (size_t)(nkv0 + srow) * QKS + sgc * 8, Ks[bi ^ 1] + tid * 8);
        async16(vtb + (size_t)srow * Tn + nkv0 + sgc * 8, Vts[bi ^ 1] + tid * 8);
      }

      if (t > tdiag) continue;   // fully-masked for this wave (wave-uniform)

      // S = Q K^T (already log2-scaled via Q)
      const u16* ks = Ks[bi];
      const u16* vs = Vts[bi];
      f32x4 s[4];
#pragma unroll
      for (int nt = 0; nt < 4; ++nt) s[nt] = (f32x4){0.f, 0.f, 0.f, 0.f};
#pragma unroll
      for (int nt = 0; nt < 4; ++nt) {
        const int rb = nt * 16 + l16;
        ushx8 b0 = *(const ushx8*)(ks + rb * 64 + (quad ^ (rb & 7)) * 8);
        ushx8 b1 = *(const ushx8*)(ks + rb * 64 + ((quad + 4) ^ (rb & 7)) * 8);
        s[nt] = mfma_bf16(qf[0], b0, s[nt]);
        s[nt] = mfma_bf16(qf[1], b1, s[nt]);
      }

      // online softmax; mask only on the wave's single diagonal tile
      if (t == tdiag) {
#pragma unroll
        for (int i = 0; i < 4; ++i) {
          const int qr = q0w + quad * 4 + i;
          float vv[4];
          float rmax = -__builtin_inff();
#pragma unroll
          for (int nt = 0; nt < 4; ++nt) {
            float v = s[nt][i];
            if ((kv0 + nt * 16 + l16) > qr) v = -__builtin_inff();
            vv[nt] = v;
            rmax = fmaxf(rmax, v);
          }
          rmax = red16max(rmax);
          const float mnew = fmaxf(mrow[i], rmax);
          const float al = __builtin_amdgcn_exp2f(mrow[i] - mnew);
          mrow[i] = mnew;
          float rsum = 0.f;
#pragma unroll
          for (int nt = 0; nt < 4; ++nt) {
            float p = __builtin_amdgcn_exp2f(vv[nt] - mnew);
            rsum += p;
            pswv[(quad * 4 + i) * 72 + nt * 16 + l16] = f2bf_rna(p);
          }
          lrow[i] = lrow[i] * al + rsum;   // per-lane partial; reduced at end
#pragma unroll
          for (int nt = 0; nt < 4; ++nt) o[nt][i] *= al;
        }
      } else {
#pragma unroll
        for (int i = 0; i < 4; ++i) {
          float rmax = fmaxf(fmaxf(s[0][i], s[1][i]), fmaxf(s[2][i], s[3][i]));
          rmax = red16max(rmax);
          const float mnew = fmaxf(mrow[i], rmax);
          const float al = __builtin_amdgcn_exp2f(mrow[i] - mnew);
          mrow[i] = mnew;
          float rsum = 0.f;
#pragma unroll
          for (int nt = 0; nt < 4; ++nt) {
            float p = __builtin_amdgcn_exp2f(s[nt][i] - mnew);
            rsum += p;
            pswv[(quad * 4 + i) * 72 + nt * 16 + l16] = f2bf_rna(p);
          }
          lrow[i] = lrow[i] * al + rsum;
#pragma unroll
          for (int nt = 0; nt < 4; ++nt) o[nt][i] *= al;
        }
      }

      // P A-fragments from wave-local LDS (DS in-order per wave, no barrier)
      ushx8 pf0, pf1;
      {
        const u16* pp = pswv + l16 * 72 + quad * 8;
        pf0 = *(const ushx8*)pp;
        pf1 = *(const ushx8*)(pp + 32);
      }

      // O += P V
#pragma unroll
      for (int nt = 0; nt < 4; ++nt) {
        const int rb = nt * 16 + l16;
        ushx8 v0 = *(const ushx8*)(vs + rb * 64 + (quad ^ (rb & 7)) * 8);
        ushx8 v1 = *(const ushx8*)(vs + rb * 64 + ((quad + 4) ^ (rb & 7)) * 8);
        o[nt] = mfma_bf16(pf0, v0, o[nt]);
        o[nt] = mfma_bf16(pf1, v1, o[nt]);
      }
    }

    // O/l (16-lane l reduction deferred to here), write y_attn bf16
#pragma unroll
    for (int i = 0; i < 4; ++i) {
      const float inv = 1.f / red16sum(lrow[i]);
      const int trow = q0w + quad * 4 + i;
      u16* op = out + ((size_t)(b * Tn + trow)) * Cn + h * Dn + l16;
#pragma unroll
      for (int nt = 0; nt < 4; ++nt) op[nt * 16] = f2bf(o[nt][i] * inv);
    }
  }
}

// ---------------- launch ----------------
extern "C" void kernel_launch(void* const* d_in, const int* in_sizes, int n_in,
                              void* d_out, int out_size, void* d_ws, size_t ws_size,
                              hipStream_t stream) {
  const float* x = (const float*)d_in[0];
  const float* w_qkv = (const float*)d_in[1];
  const float* w_proj = (const float*)d_in[2];
  const float* b_proj = (const float*)d_in[3];
  float* out = (float*)d_out;
  char* ws = (char*)d_ws;

  u16* xb     = (u16*)(ws);                 // 16 MiB @ 0
  u16* wqkvb  = (u16*)(ws + 16777216);      //  6 MiB @ 16
  u16* wprojb = (u16*)(ws + 23068672);      //  2 MiB @ 22
  u16* qkb    = (u16*)(ws + 25165824);      // 32 MiB @ 24  (packed QK, stride 2048)
  u16* vtb    = (u16*)(ws + 58720256);      // 16 MiB @ 56
  u16* yb     = (u16*)(ws + 75497472);      // 16 MiB @ 72  (ends 88 MiB)

  cast3_kernel<<<12288, 256, 0, stream>>>(x, xb, 2097152,
                                          w_qkv, wqkvb, 786432,
                                          w_proj, wprojb, 262144);

  // QKV: 32 m-tiles x 24 n-tiles = 768 blocks = 3.0 exact rounds
  gemm_8ph<1><<<768, 512, 0, stream>>>(xb, wqkvb, (void*)qkb, vtb, nullptr);

  attn_kernel<<<dim3(4, Hn, Bn), 512, 0, stream>>>(qkb, vtb, yb);

  // proj: 32 m-tiles x 8 n-tiles = 256 blocks = 1.0 exact round
  gemm_8ph<0><<<256, 512, 0, stream>>>(yb, wprojb, (void*)out, nullptr, b_proj);
}